// Round 6
// baseline (6001.087 us; speedup 1.0000x reference)
//
#include <hip/hip_runtime.h>
#include <hip/hip_bf16.h>

#define TT 256
#define D 1024
#define BD (128 * 1024)
#define NWPL 85
#define NWG 256
#define NUSED 255
#define ROWLEN 1048  // bank step 12 mod 32 -> ~2-way-free b128 LDS reads; 78*1048*2=163,488B

typedef __attribute__((ext_vector_type(8))) short bf16x8;
typedef __attribute__((ext_vector_type(4))) float f32x4;

__device__ __forceinline__ unsigned short f2bf(float f) {
    __hip_bfloat16 h = __float2bfloat16(f);
    return *reinterpret_cast<unsigned short*>(&h);
}
__device__ __forceinline__ float bf2f(unsigned short u) {
    unsigned v = (unsigned)u << 16;
    return __builtin_bit_cast(float, v);
}

__global__ __launch_bounds__(256) void cvt_f32_bf16(const float* __restrict__ in,
                                                    unsigned short* __restrict__ out, int n) {
    int i = (blockIdx.x * 256 + threadIdx.x) * 8;
    if (i + 8 <= n) {
        float4 a = *(const float4*)(in + i);
        float4 b = *(const float4*)(in + i + 4);
        unsigned short t[8] = { f2bf(a.x), f2bf(a.y), f2bf(a.z), f2bf(a.w),
                                f2bf(b.x), f2bf(b.y), f2bf(b.z), f2bf(b.w) };
        *(uint4*)(out + i) = *(const uint4*)t;
    }
}

// Persistent point-to-point dataflow dilated-GRU.
// prog[layer*128 + u] = number of cells slice (layer,u) has completed (release-published).
// Each WG runs its own t-loop; waits only on true dataflow predecessors.
__global__ __launch_bounds__(256, 1) void dgru_dataflow(
    const unsigned short* __restrict__ xbf,
    const float* __restrict__ Wih, const float* __restrict__ Whh,
    const float* __restrict__ bih, const float* __restrict__ bhh,
    unsigned short* __restrict__ ring_bf, float* __restrict__ ring_f,  // 14 slots: l0@0(R2), l1@2(R4), l2@6(R8)
    unsigned short* __restrict__ hin_ring,                             // 2 pairs x 8 slots
    float* __restrict__ out,
    unsigned* __restrict__ prog)
{
    __shared__ unsigned short wlds[78 * ROWLEN];

    const int grp = blockIdx.x & 7;
    const int p = 32 * grp + (blockIdx.x >> 3);  // XCD-packing heuristic (perf only)
    if (p >= NUSED) return;                      // spare WG: nothing depends on it
    const int layer = p / NWPL;
    const int u     = p % NWPL;
    const int ncols = (u < 4) ? 13 : 12;
    const int c0    = u * 12 + (u < 4 ? u : 4);

    // ---- one-time: weight slice fp32 -> bf16 -> LDS (stationary)
    {
        const float* w0 = Wih + (size_t)layer * 3 * D * D;
        const float* w1 = Whh + (size_t)layer * 3 * D * D;
        const int nrows = 6 * ncols;
        for (int rid = 0; rid < nrows; ++rid) {
            int m   = rid / (3 * ncols);
            int rem = rid - m * 3 * ncols;
            int g   = rem / ncols;
            int c   = rem - g * ncols;
            const float* src = (m ? w1 : w0) + ((size_t)g * D + c0 + c) * D + threadIdx.x * 4;
            float4 v = *(const float4*)src;
            ushort4 o = { f2bf(v.x), f2bf(v.y), f2bf(v.z), f2bf(v.w) };
            *(ushort4*)&wlds[rid * ROWLEN + threadIdx.x * 4] = o;
        }
        __syncthreads();
    }

    const int tid  = threadIdx.x;
    const int wave = tid >> 6;
    const int lane = tid & 63;
    const int r15  = lane & 15;
    const int kq   = lane >> 4;
    const int kq8  = kq * 8;
    const int c_cl = (r15 < ncols) ? r15 : (ncols - 1);
    const bool cvalid = r15 < ncols;
    const int col  = c0 + c_cl;

    const float bi2 = bih[layer * 3 * D + 2 * D + col];
    const float bh2 = bhh[layer * 3 * D + 2 * D + col];
    const float bs0 = bih[layer * 3 * D + col] + bhh[layer * 3 * D + col];
    const float bs1 = bih[layer * 3 * D + D + col] + bhh[layer * 3 * D + D + col];

    const unsigned short* bp[6];
    #pragma unroll
    for (int mg = 0; mg < 6; ++mg) bp[mg] = wlds + (mg * ncols + c_cl) * ROWLEN;

    const int arow_off0 = (wave * 32 + r15) * D;
    const int arow_off1 = (wave * 32 + 16 + r15) * D;

    const int dil = 1 << layer;
    const int R   = 2 << layer;                      // ring size 2^(l+1): reuse-safe
    const int rb  = (layer == 0) ? 0 : (layer == 1 ? 2 : 6);

    unsigned* pr0 = prog;
    unsigned* pr1 = prog + 128;
    unsigned* pr2 = prog + 256;
    unsigned* myflag = prog + layer * 128 + u;

    // wait-set pointers (thresholds per t below); a3 may be unused (th<=0)
    unsigned *a1, *a2, *a3;
    if (layer == 0)      { a1 = pr0; a2 = pr1; a3 = pr2; }
    else if (layer == 1) { a1 = pr0; a2 = pr1; a3 = pr2; }
    else                 { a1 = pr1; a2 = pr2; a3 = pr2; }

    const int j2 = (lane < 21) ? lane + 64 : lane;   // lanes cover flags [0,85) x2

    for (int t = 0; t < TT; ++t) {
        int th1, th2, th3;
        if (layer == 0)      { th1 = t;     th2 = t - 7; th3 = 0; }      // hprev; backpressure
        else if (layer == 1) { th1 = t + 1; th2 = t - 1; th3 = t - 7; }  // hin; hprev; backpressure
        else                 { th1 = t + 1; th2 = t - 3; th3 = 0; }      // hin; hprev

        if (wave == 0) {
            for (;;) {
                bool ok = true;
                if (th1 > 0) ok = ok && (int)__hip_atomic_load(a1 + lane, __ATOMIC_RELAXED, __HIP_MEMORY_SCOPE_AGENT) >= th1
                                     && (int)__hip_atomic_load(a1 + j2,   __ATOMIC_RELAXED, __HIP_MEMORY_SCOPE_AGENT) >= th1;
                if (th2 > 0) ok = ok && (int)__hip_atomic_load(a2 + lane, __ATOMIC_RELAXED, __HIP_MEMORY_SCOPE_AGENT) >= th2
                                     && (int)__hip_atomic_load(a2 + j2,   __ATOMIC_RELAXED, __HIP_MEMORY_SCOPE_AGENT) >= th2;
                if (th3 > 0) ok = ok && (int)__hip_atomic_load(a3 + lane, __ATOMIC_RELAXED, __HIP_MEMORY_SCOPE_AGENT) >= th3
                                     && (int)__hip_atomic_load(a3 + j2,   __ATOMIC_RELAXED, __HIP_MEMORY_SCOPE_AGENT) >= th3;
                if (__all(ok)) break;
                __builtin_amdgcn_s_sleep(1);
            }
            __builtin_amdgcn_fence(__ATOMIC_ACQUIRE, "agent");  // inv L1/L2: see producers' data
        }
        __syncthreads();

        const unsigned short* hinb = layer ? hin_ring + (size_t)((layer - 1) * 8 + (t & 7)) * BD
                                           : xbf + (size_t)t * BD;
        const int rs = (t + dil) % R, wsl = t % R;               // (t-dil)%R == (t+dil)%R since R=2*dil
        const unsigned short* hprevb = ring_bf + (size_t)(rb + rs) * BD;
        const float*  hprevf = ring_f + (size_t)(rb + rs) * BD;
        float*        houtf  = ring_f + (size_t)(rb + wsl) * BD;
        unsigned short* houtb = ring_bf + (size_t)(rb + wsl) * BD;

        // ---- epilogue operand prefetch (returns under the GEMM)
        float hpv[8], rsv[8];
        #pragma unroll
        for (int rtl = 0; rtl < 2; ++rtl)
            #pragma unroll
            for (int q = 0; q < 4; ++q) {
                const int row = wave * 32 + rtl * 16 + kq * 4 + q;
                const size_t idx = (size_t)row * D + col;
                hpv[rtl * 4 + q] = hprevf[idx];
                rsv[rtl * 4 + q] = bf2f(hinb[idx]);
            }

        f32x4 acc[2][2][3] = {};
        bf16x8 A0[16], A1[16], A2[16];

#define ISSUE1(Av, KS, SL) { \
        Av[(SL) * 4 + 0] = *(const bf16x8*)(hinb   + arow_off0 + (KS) * 32 + kq8); \
        Av[(SL) * 4 + 1] = *(const bf16x8*)(hprevb + arow_off0 + (KS) * 32 + kq8); \
        Av[(SL) * 4 + 2] = *(const bf16x8*)(hinb   + arow_off1 + (KS) * 32 + kq8); \
        Av[(SL) * 4 + 3] = *(const bf16x8*)(hprevb + arow_off1 + (KS) * 32 + kq8); }
#define ISSUEG(Av, BASE) { ISSUE1(Av, (BASE) + 0, 0) ISSUE1(Av, (BASE) + 1, 1) \
                           ISSUE1(Av, (BASE) + 2, 2) ISSUE1(Av, (BASE) + 3, 3) \
                           __builtin_amdgcn_sched_barrier(0); }
#define COMPG(Av, BASE) { _Pragma("unroll") for (int kk = 0; kk < 4; ++kk) { \
        bf16x8 Bv[6]; \
        _Pragma("unroll") for (int mg = 0; mg < 6; ++mg) \
            Bv[mg] = *(const bf16x8*)(bp[mg] + ((BASE) + kk) * 32 + kq8); \
        _Pragma("unroll") for (int g = 0; g < 3; ++g) { \
            acc[0][0][g] = __builtin_amdgcn_mfma_f32_16x16x32_bf16(Av[kk * 4 + 0], Bv[g],     acc[0][0][g], 0, 0, 0); \
            acc[0][1][g] = __builtin_amdgcn_mfma_f32_16x16x32_bf16(Av[kk * 4 + 1], Bv[3 + g], acc[0][1][g], 0, 0, 0); \
            acc[1][0][g] = __builtin_amdgcn_mfma_f32_16x16x32_bf16(Av[kk * 4 + 2], Bv[g],     acc[1][0][g], 0, 0, 0); \
            acc[1][1][g] = __builtin_amdgcn_mfma_f32_16x16x32_bf16(Av[kk * 4 + 3], Bv[3 + g], acc[1][1][g], 0, 0, 0); } } \
        __builtin_amdgcn_sched_barrier(0); }

        ISSUEG(A0, 0);  ISSUEG(A1, 4);  ISSUEG(A2, 8);
        COMPG(A0, 0);   ISSUEG(A0, 12);
        COMPG(A1, 4);   ISSUEG(A1, 16);
        COMPG(A2, 8);   ISSUEG(A2, 20);
        COMPG(A0, 12);  ISSUEG(A0, 24);
        COMPG(A1, 16);  ISSUEG(A1, 28);
        COMPG(A2, 20);
        COMPG(A0, 24);
        COMPG(A1, 28);

        // ---- gates + residual; sc1 stores (MALL-direct, cross-XCD coherent)
        #pragma unroll
        for (int rtl = 0; rtl < 2; ++rtl) {
            #pragma unroll
            for (int q = 0; q < 4; ++q) {
                const int row = wave * 32 + rtl * 16 + kq * 4 + q;
                const size_t idx = (size_t)row * D + col;
                float xr = acc[rtl][0][0][q] + acc[rtl][1][0][q] + bs0;
                float xz = acc[rtl][0][1][q] + acc[rtl][1][1][q] + bs1;
                float rg = 1.f / (1.f + __expf(-xr));
                float zg = 1.f / (1.f + __expf(-xz));
                float ng = tanhf(acc[rtl][0][2][q] + bi2 + rg * (acc[rtl][1][2][q] + bh2));
                float hp = hpv[rtl * 4 + q];
                float h  = (1.f - zg) * ng + zg * hp;
                float v = (h + rsv[rtl * 4 + q]) * 0.70710678f;
                float y = v > 0.f ? v : 0.2f * v;
                if (cvalid) {
                    __hip_atomic_store(&houtf[idx], h, __ATOMIC_RELAXED, __HIP_MEMORY_SCOPE_AGENT);
                    __hip_atomic_store(&houtb[idx], f2bf(h), __ATOMIC_RELAXED, __HIP_MEMORY_SCOPE_AGENT);
                    if (layer == 2) {
                        __hip_atomic_store(&out[(size_t)t * BD + idx], y, __ATOMIC_RELAXED, __HIP_MEMORY_SCOPE_AGENT);
                    } else {
                        __hip_atomic_store(&hin_ring[(size_t)(layer * 8 + (t & 7)) * BD + idx],
                                           f2bf(y), __ATOMIC_RELAXED, __HIP_MEMORY_SCOPE_AGENT);
                    }
                }
            }
        }

        __syncthreads();  // drains all 4 waves' stores (vmcnt 0) before publishing
        if (tid == 0) {
            __builtin_amdgcn_fence(__ATOMIC_RELEASE, "agent");
            __hip_atomic_store(myflag, (unsigned)(t + 1), __ATOMIC_RELAXED, __HIP_MEMORY_SCOPE_AGENT);
        }
    }
}

extern "C" void kernel_launch(void* const* d_in, const int* in_sizes, int n_in,
                              void* d_out, int out_size, void* d_ws, size_t ws_size,
                              hipStream_t stream) {
    const float* x   = (const float*)d_in[0];
    const float* Wih = (const float*)d_in[1];
    const float* Whh = (const float*)d_in[2];
    const float* bih = (const float*)d_in[3];
    const float* bhh = (const float*)d_in[4];
    float* out = (float*)d_out;

    char* ws = (char*)d_ws;
    size_t off = 0;
    auto alloc = [&](size_t bytes) -> void* {
        void* p = ws + off;
        off += (bytes + 255) & ~(size_t)255;
        return p;
    };

    const int NX = TT * BD;
    unsigned short* xbf = (unsigned short*)alloc((size_t)NX * 2);

    size_t zstart = off;
    unsigned short* ring_bf  = (unsigned short*)alloc((size_t)14 * BD * 2);
    float*          ring_f   = (float*)alloc((size_t)14 * BD * 4);
    unsigned short* hin_ring = (unsigned short*)alloc((size_t)16 * BD * 2);
    unsigned*       prog     = (unsigned*)alloc(2048);
    size_t zbytes = off - zstart;

    cvt_f32_bf16<<<NX / 8 / 256, 256, 0, stream>>>(x, xbf, NX);
    hipMemsetAsync(ws + zstart, 0, zbytes, stream);

    dgru_dataflow<<<NWG, 256, 0, stream>>>(
        xbf, Wih, Whh, bih, bhh,
        ring_bf, ring_f, hin_ring, out,
        prog);
}